// Round 4
// baseline (338.820 us; speedup 1.0000x reference)
//
#include <hip/hip_runtime.h>

// Causal self-attention, S=4096, E=D=1024, fp32 in/out.
// R4: S = x*(Wq Wk^T)*x^T restructure (kills K-GEMM + transposes);
//     y-GEMM + Vt-GEMM merged (512 blocks); S-GEMM split-K=2 (1056 blocks,
//     fixes 528/256 grid quantization = 68.75% util found in R3);
//     PV split KC=512 (1152 blocks). ws 106MB.

typedef unsigned short u16;
typedef unsigned int   u32;
typedef __bf16 bf16x8 __attribute__((ext_vector_type(8)));
typedef float  f32x4  __attribute__((ext_vector_type(4)));

#define SLEN 4096
#define EDIM 1024

__device__ __forceinline__ u16 f2bf(float x) {
    union { float f; u32 u; } c; c.f = x;
    return (u16)((c.u + 0x7FFFu + ((c.u >> 16) & 1u)) >> 16);
}
__device__ __forceinline__ float bf2f(u16 h) {
    union { u32 u; float f; } c; c.u = ((u32)h) << 16;
    return c.f;
}

__device__ __forceinline__ void gll16(const u16* g, u16* l) {
    __builtin_amdgcn_global_load_lds(
        (const __attribute__((address_space(1))) void*)g,
        (__attribute__((address_space(3))) void*)l, 16, 0, 0);
}

// ---------------- elementwise split: v -> hi bf16, lo bf16 ----------------
__global__ __launch_bounds__(256) void k_split(const float* __restrict__ in,
                                               u16* __restrict__ hi,
                                               u16* __restrict__ lo, int n4) {
    int i = blockIdx.x * 256 + threadIdx.x;
    if (i >= n4) return;
    const float4 v = reinterpret_cast<const float4*>(in)[i];
    u16 h0 = f2bf(v.x), h1 = f2bf(v.y), h2 = f2bf(v.z), h3 = f2bf(v.w);
    ushort4 hv = make_ushort4(h0, h1, h2, h3);
    ushort4 lv = make_ushort4(f2bf(v.x - bf2f(h0)), f2bf(v.y - bf2f(h1)),
                              f2bf(v.z - bf2f(h2)), f2bf(v.w - bf2f(h3)));
    reinterpret_cast<ushort4*>(hi)[i] = hv;
    reinterpret_cast<ushort4*>(lo)[i] = lv;
}

// ------------- transpose + split: in (R x C) f32 -> out (C x R) bf16 -------
template <bool WITH_LO>
__global__ __launch_bounds__(256) void k_tsplit(const float* __restrict__ in,
                                                u16* __restrict__ oh,
                                                u16* __restrict__ ol,
                                                int R, int C) {
    __shared__ float tile[32][33];
    int tx = threadIdx.x, ty = threadIdx.y;  // 32 x 8
    int c0 = blockIdx.x * 32, r0 = blockIdx.y * 32;
#pragma unroll
    for (int r = 0; r < 4; r++)
        tile[ty + r * 8][tx] = in[(size_t)(r0 + ty + r * 8) * C + (c0 + tx)];
    __syncthreads();
#pragma unroll
    for (int r = 0; r < 4; r++) {
        float v = tile[tx][ty + r * 8];
        size_t o = (size_t)(c0 + ty + r * 8) * R + (r0 + tx);
        u16 h = f2bf(v);
        oh[o] = h;
        if constexpr (WITH_LO) ol[o] = f2bf(v - bf2f(h));
    }
}

// ---------------- GEMM core: 128x128 tile, BK=32, global_load_lds ----------
template <int TERMS>
__device__ __forceinline__ void gemm_core(
    u16* smem,
    const u16* __restrict__ Ah, const u16* __restrict__ Al,
    const u16* __restrict__ Bh, const u16* __restrict__ Bl,
    int K, int kbeg, int kend, int rowA0, int rowB0,
    int tid, f32x4 (&acc)[4][4]) {
    constexpr int NB = (TERMS == 3) ? 2 : 1;
    const int lane = tid & 63, wv = tid >> 6;
    const int wm = (wv >> 1) * 64, wn = (wv & 1) * 64;
    const int l15 = lane & 15, lq = lane >> 4;

    const u16* srcs[2 * NB];
    if constexpr (TERMS == 3) {
        srcs[0] = Ah + (size_t)rowA0 * K;
        srcs[1] = Al + (size_t)rowA0 * K;
        srcs[2] = Bh + (size_t)rowB0 * K;
        srcs[3] = Bl + (size_t)rowB0 * K;
    } else {
        srcs[0] = Ah + (size_t)rowA0 * K;
        srcs[1] = Bh + (size_t)rowB0 * K;
    }
    const u16* sAh = smem;
    const u16* sAl = smem + 4096;
    const u16* sBh = smem + ((TERMS == 3) ? 8192 : 4096);
    const u16* sBl = smem + 12288;

    for (int k0 = kbeg; k0 < kend; k0 += 32) {
#pragma unroll
        for (int i = 0; i < 4 * NB; i++) {
            int c = ((i & 1) << 8) + (wv << 6) + lane;  // chunk within tile
            int m = c >> 2, kb = c & 3;
            const u16* g = srcs[i >> 1] + (size_t)m * K + (k0 + kb * 8);
            u16* l = smem + (size_t)((i << 8) + (wv << 6) + lane) * 8;
            gll16(g, l);
        }
        __syncthreads();

        bf16x8 ah[4], bh[4];
#pragma unroll
        for (int i = 0; i < 4; i++) {
            ah[i] = *(const bf16x8*)(sAh + (wm + i * 16 + l15) * 32 + lq * 8);
            bh[i] = *(const bf16x8*)(sBh + (wn + i * 16 + l15) * 32 + lq * 8);
        }
        if constexpr (TERMS == 3) {
            bf16x8 al[4], bl[4];
#pragma unroll
            for (int i = 0; i < 4; i++) {
                al[i] = *(const bf16x8*)(sAl + (wm + i * 16 + l15) * 32 + lq * 8);
                bl[i] = *(const bf16x8*)(sBl + (wn + i * 16 + l15) * 32 + lq * 8);
            }
#pragma unroll
            for (int mi = 0; mi < 4; mi++)
#pragma unroll
                for (int ni = 0; ni < 4; ni++) {
                    acc[mi][ni] = __builtin_amdgcn_mfma_f32_16x16x32_bf16(ah[mi], bh[ni], acc[mi][ni], 0, 0, 0);
                    acc[mi][ni] = __builtin_amdgcn_mfma_f32_16x16x32_bf16(ah[mi], bl[ni], acc[mi][ni], 0, 0, 0);
                    acc[mi][ni] = __builtin_amdgcn_mfma_f32_16x16x32_bf16(al[mi], bh[ni], acc[mi][ni], 0, 0, 0);
                }
        } else {
#pragma unroll
            for (int mi = 0; mi < 4; mi++)
#pragma unroll
                for (int ni = 0; ni < 4; ni++)
                    acc[mi][ni] = __builtin_amdgcn_mfma_f32_16x16x32_bf16(ah[mi], bh[ni], acc[mi][ni], 0, 0, 0);
        }
        __syncthreads();
    }
}

// ---- Mt = Wk * Wq^T (Mt[e2][e1] = sum_d Wk[e2][d] Wq[e1][d]), split-K=8 ----
__global__ __launch_bounds__(256) void k_gemm_m(
    const u16* __restrict__ Wkh, const u16* __restrict__ Wkl,
    const u16* __restrict__ Wqh, const u16* __restrict__ Wql,
    float* __restrict__ Mtf) {
    __shared__ u16 smem[16384];
    f32x4 acc[4][4] = {};
    const int rowA0 = blockIdx.y * 128, rowB0 = blockIdx.x * 128;
    const int kbeg = blockIdx.z * 128;
    gemm_core<3>(smem, Wkh, Wkl, Wqh, Wql, EDIM, kbeg, kbeg + 128, rowA0, rowB0, threadIdx.x, acc);
    const int lane = threadIdx.x & 63, wv = threadIdx.x >> 6;
    const int wm = (wv >> 1) * 64, wn = (wv & 1) * 64;
    const int l15 = lane & 15, lq = lane >> 4;
#pragma unroll
    for (int mi = 0; mi < 4; mi++)
#pragma unroll
        for (int ni = 0; ni < 4; ni++)
#pragma unroll
            for (int r = 0; r < 4; r++)
                atomicAdd(&Mtf[(size_t)(rowA0 + wm + mi * 16 + lq * 4 + r) * EDIM +
                               (rowB0 + wn + ni * 16 + l15)], acc[mi][ni][r]);
}

// ---- merged: b<256: y = x*M^T (TERMS=3, split epi); else Vt = Wv^T*x^T ----
__global__ __launch_bounds__(256) void k_gemm_yv(
    const u16* __restrict__ xh, const u16* __restrict__ xl,
    const u16* __restrict__ Mth, const u16* __restrict__ Mtl,
    const u16* __restrict__ Wvth,
    u16* __restrict__ yh, u16* __restrict__ yl, u16* __restrict__ Vt) {
    __shared__ u16 smem[16384];
    f32x4 acc[4][4] = {};
    const int b = blockIdx.x;
    const int lane = threadIdx.x & 63, wv = threadIdx.x >> 6;
    const int wm = (wv >> 1) * 64, wn = (wv & 1) * 64;
    const int l15 = lane & 15, lq = lane >> 4;
    if (b < 256) {
        int tm = b >> 3, tn = b & 7;
        gemm_core<3>(smem, xh, xl, Mth, Mtl, EDIM, 0, EDIM, tm * 128, tn * 128, threadIdx.x, acc);
#pragma unroll
        for (int mi = 0; mi < 4; mi++)
#pragma unroll
            for (int ni = 0; ni < 4; ni++)
#pragma unroll
                for (int r = 0; r < 4; r++) {
                    size_t o = (size_t)(tm * 128 + wm + mi * 16 + lq * 4 + r) * EDIM +
                               (tn * 128 + wn + ni * 16 + l15);
                    float v = acc[mi][ni][r];
                    u16 h = f2bf(v);
                    yh[o] = h;
                    yl[o] = f2bf(v - bf2f(h));
                }
    } else {
        int b2 = b - 256;
        int tm = b2 & 7, tn = b2 >> 3;  // Vt is [1024=d rows][4096=s cols]
        gemm_core<1>(smem, Wvth, nullptr, xh, nullptr, EDIM, 0, EDIM, tm * 128, tn * 128, threadIdx.x, acc);
#pragma unroll
        for (int mi = 0; mi < 4; mi++)
#pragma unroll
            for (int ni = 0; ni < 4; ni++)
#pragma unroll
                for (int r = 0; r < 4; r++) {
                    size_t o = (size_t)(tm * 128 + wm + mi * 16 + lq * 4 + r) * SLEN +
                               (tn * 128 + wn + ni * 16 + l15);
                    Vt[o] = f2bf(acc[mi][ni][r]);
                }
    }
}

// ---- S = y*x^T /32, lower-tri tiles, split-K=2, packed partial outputs ----
__global__ __launch_bounds__(256) void k_gemm_s(
    const u16* __restrict__ yh, const u16* __restrict__ yl,
    const u16* __restrict__ xh, const u16* __restrict__ xl,
    float* __restrict__ Spk0, float* __restrict__ Spk1) {
    __shared__ u16 smem[16384];
    int b = blockIdx.x;
    int half = (b >= 528) ? 1 : 0;
    int t = b - half * 528;
    int ti = (int)((sqrtf(8.0f * (float)t + 1.0f) - 1.0f) * 0.5f);
    while ((ti + 1) * (ti + 2) / 2 <= t) ti++;
    while (ti * (ti + 1) / 2 > t) ti--;
    int tm = ti, tn = t - ti * (ti + 1) / 2;
    f32x4 acc[4][4] = {};
    gemm_core<3>(smem, yh, yl, xh, xl, EDIM, half * 512, half * 512 + 512,
                 tm * 128, tn * 128, threadIdx.x, acc);
    const int lane = threadIdx.x & 63, wv = threadIdx.x >> 6;
    const int wm = (wv >> 1) * 64, wn = (wv & 1) * 64;
    const int l15 = lane & 15, lq = lane >> 4;
    float* Cb = (half ? Spk1 : Spk0) + (size_t)t * 16384;
#pragma unroll
    for (int mi = 0; mi < 4; mi++)
#pragma unroll
        for (int ni = 0; ni < 4; ni++)
#pragma unroll
            for (int r = 0; r < 4; r++)
                Cb[(wm + mi * 16 + lq * 4 + r) * 128 + (wn + ni * 16 + l15)] =
                    acc[mi][ni][r] * 0.03125f;
}

// ---------------- PV GEMM: split-K (KC=512), atomic for tm>=4 --------------
__global__ __launch_bounds__(256) void k_gemm_pv(
    const u16* __restrict__ P, const u16* __restrict__ Vt,
    float* __restrict__ C) {
    __shared__ u16 smem[8192];
    int tn = blockIdx.x;
    int y = blockIdx.y, tm = 0;
    for (;;) {
        int nc = (tm + 4) >> 2;  // ceil((tm+1)/4)
        if (y < nc) break;
        y -= nc; tm++;
    }
    int kbeg = y * 512;
    int kend = min((tm + 1) * 128, kbeg + 512);
    f32x4 acc[4][4] = {};
    gemm_core<1>(smem, P, nullptr, Vt, nullptr, SLEN, kbeg, kend, tm * 128, tn * 128, threadIdx.x, acc);
    const int lane = threadIdx.x & 63, wv = threadIdx.x >> 6;
    const int wm = (wv >> 1) * 64, wn = (wv & 1) * 64;
    const int l15 = lane & 15, lq = lane >> 4;
    bool multi = (tm >= 4);
#pragma unroll
    for (int mi = 0; mi < 4; mi++)
#pragma unroll
        for (int ni = 0; ni < 4; ni++)
#pragma unroll
            for (int r = 0; r < 4; r++) {
                size_t o = (size_t)(tm * 128 + wm + mi * 16 + lq * 4 + r) * EDIM +
                           (tn * 128 + wn + ni * 16 + l15);
                if (multi) atomicAdd(&C[o], acc[mi][ni][r]);
                else       C[o] = acc[mi][ni][r];
            }
}

// ---------------- row softmax over packed S halves -> P bf16 ----------------
__global__ __launch_bounds__(256) void k_softmax(const float* __restrict__ Spk0,
                                                 const float* __restrict__ Spk1,
                                                 u16* __restrict__ P) {
    __shared__ float buf[SLEN];
    __shared__ float red[4];
    int row = blockIdx.x;
    int tid = threadIdx.x;
    int lane = tid & 63, wid = tid >> 6;
    int n = row + 1;
    int tm = row >> 7, rl = row & 127;
    size_t base = (size_t)(tm * (tm + 1) / 2) * 16384 + rl * 128;
    const float* srow0 = Spk0 + base;
    const float* srow1 = Spk1 + base;

    float m = -3.0e38f;
    for (int j = tid; j < n; j += 256) {
        size_t idx = (size_t)(j >> 7) * 16384 + (j & 127);
        float v = srow0[idx] + srow1[idx];
        buf[j] = v;
        m = fmaxf(m, v);
    }
#pragma unroll
    for (int o = 32; o; o >>= 1) m = fmaxf(m, __shfl_xor(m, o));
    if (lane == 0) red[wid] = m;
    __syncthreads();
    m = fmaxf(fmaxf(red[0], red[1]), fmaxf(red[2], red[3]));
    __syncthreads();

    float s = 0.f;
    for (int j = tid; j < n; j += 256) {
        float e = __expf(buf[j] - m);
        buf[j] = e;
        s += e;
    }
#pragma unroll
    for (int o = 32; o; o >>= 1) s += __shfl_xor(s, o);
    if (lane == 0) red[wid] = s;
    __syncthreads();
    s = red[0] + red[1] + red[2] + red[3];
    float inv = 1.0f / s;

    u16* prow = P + (size_t)row * SLEN;
    for (int j = tid; j < n; j += 256) prow[j] = f2bf(buf[j] * inv);
    // zero tail up to 128-boundary (PV stages it; P overlays dead xh..yl)
    int jend = ((row >> 7) + 1) << 7;
    for (int j = n + tid; j < jend; j += 256) prow[j] = 0;
}

// ---------------------------------------------------------------------------
extern "C" void kernel_launch(void* const* d_in, const int* in_sizes, int n_in,
                              void* d_out, int out_size, void* d_ws, size_t ws_size,
                              hipStream_t stream) {
    const float* x  = (const float*)d_in[0];
    const float* Wq = (const float*)d_in[1];
    const float* Wk = (const float*)d_in[2];
    const float* Wv = (const float*)d_in[3];
    float* out = (float*)d_out;
    char* ws = (char*)d_ws;
    const size_t MB = 1024 * 1024;

    // persistent regions
    u16* xh = (u16*)(ws + 0 * MB);     // 8MB, live until S-GEMM
    u16* xl = (u16*)(ws + 8 * MB);     // 8MB
    u16* yh = (u16*)(ws + 16 * MB);    // 8MB
    u16* yl = (u16*)(ws + 24 * MB);    // 8MB
    u16* Vt = (u16*)(ws + 32 * MB);    // 8MB, live until PV
    float* Spk0 = (float*)(ws + 40 * MB);  // 33MB  [40,73)
    float* Spk1 = (float*)(ws + 73 * MB);  // 33MB  [73,106)
    // transients inside [40,106) -- all dead before k_gemm_s writes Spk
    u16* Wqh  = (u16*)(ws + 40 * MB);
    u16* Wql  = (u16*)(ws + 42 * MB);
    u16* Wkh  = (u16*)(ws + 44 * MB);
    u16* Wkl  = (u16*)(ws + 46 * MB);
    u16* Wvth = (u16*)(ws + 48 * MB);
    float* Mtf = (float*)(ws + 50 * MB);   // 4MB
    u16* Mth  = (u16*)(ws + 54 * MB);
    u16* Mtl  = (u16*)(ws + 56 * MB);      // -58
    // P overlays xh..yl (dead after S-GEMM)
    u16* Pb = (u16*)(ws + 0 * MB);         // 32MB

    dim3 b256(256);
    dim3 tb(32, 8);

    // 1) splits / transpose
    k_split<<<4096, b256, 0, stream>>>(x, xh, xl, (SLEN * EDIM) / 4);
    k_split<<<1024, b256, 0, stream>>>(Wq, Wqh, Wql, (EDIM * EDIM) / 4);
    k_split<<<1024, b256, 0, stream>>>(Wk, Wkh, Wkl, (EDIM * EDIM) / 4);
    k_tsplit<false><<<dim3(32, 32), tb, 0, stream>>>(Wv, Wvth, nullptr, EDIM, EDIM);

    // 2) Mt = Wk*Wq^T (split-K=8, atomics), then split to hi/lo
    hipMemsetAsync(Mtf, 0, (size_t)EDIM * EDIM * sizeof(float), stream);
    k_gemm_m<<<dim3(8, 8, 8), b256, 0, stream>>>(Wkh, Wkl, Wqh, Wql, Mtf);
    k_split<<<1024, b256, 0, stream>>>(Mtf, Mth, Mtl, (EDIM * EDIM) / 4);

    // 3) y = x*M^T (split epi) + Vt = Wv^T*x^T, one 512-block dispatch
    k_gemm_yv<<<512, b256, 0, stream>>>(xh, xl, Mth, Mtl, Wvth, yh, yl, Vt);

    // 4) S = y*x^T /32, tri tiles, split-K=2 (1056 blocks)
    k_gemm_s<<<1056, b256, 0, stream>>>(yh, yl, xh, xl, Spk0, Spk1);

    // 5) softmax (sums the two K-halves) -> P bf16
    k_softmax<<<SLEN, b256, 0, stream>>>(Spk0, Spk1, Pb);

    // 6) out = P@V, split-K KC=512 (grid 8 x 144), atomics for tm>=4
    hipMemsetAsync(d_out, 0, (size_t)out_size * sizeof(float), stream);
    k_gemm_pv<<<dim3(8, 144), b256, 0, stream>>>(Pb, Vt, out);
}

// Round 5
// 314.065 us; speedup vs baseline: 1.0788x; 1.0788x over previous
//
#include <hip/hip_runtime.h>

// Causal self-attention, S=4096, E=D=1024, fp32 in/out.
// R5: 32x32x16 MFMA (2495 vs 2075 TF ubench, half the MFMA instr count);
//     k_gemm_m via 4 partial buffers + fused reduce-split (no atomics/memset);
//     PV KC=1024 (38MB atomic vs 73MB); fused Wq/Wk split. 10 dispatches.

typedef unsigned short u16;
typedef unsigned int   u32;
typedef __bf16 bf16x8 __attribute__((ext_vector_type(8)));
typedef float  f32x16 __attribute__((ext_vector_type(16)));

#define SLEN 4096
#define EDIM 1024

__device__ __forceinline__ u16 f2bf(float x) {
    union { float f; u32 u; } c; c.f = x;
    return (u16)((c.u + 0x7FFFu + ((c.u >> 16) & 1u)) >> 16);
}
__device__ __forceinline__ float bf2f(u16 h) {
    union { u32 u; float f; } c; c.u = ((u32)h) << 16;
    return c.f;
}

__device__ __forceinline__ void gll16(const u16* g, u16* l) {
    __builtin_amdgcn_global_load_lds(
        (const __attribute__((address_space(1))) void*)g,
        (__attribute__((address_space(3))) void*)l, 16, 0, 0);
}

// ---------------- elementwise split: v -> hi bf16, lo bf16 ----------------
__global__ __launch_bounds__(256) void k_split(const float* __restrict__ in,
                                               u16* __restrict__ hi,
                                               u16* __restrict__ lo, int n4) {
    int i = blockIdx.x * 256 + threadIdx.x;
    if (i >= n4) return;
    const float4 v = reinterpret_cast<const float4*>(in)[i];
    u16 h0 = f2bf(v.x), h1 = f2bf(v.y), h2 = f2bf(v.z), h3 = f2bf(v.w);
    reinterpret_cast<ushort4*>(hi)[i] = make_ushort4(h0, h1, h2, h3);
    reinterpret_cast<ushort4*>(lo)[i] =
        make_ushort4(f2bf(v.x - bf2f(h0)), f2bf(v.y - bf2f(h1)),
                     f2bf(v.z - bf2f(h2)), f2bf(v.w - bf2f(h3)));
}

// -------- fused split of two equal-size arrays (Wq, Wk) --------------------
__global__ __launch_bounds__(256) void k_split2(
    const float* __restrict__ a, const float* __restrict__ b,
    u16* __restrict__ ah, u16* __restrict__ al,
    u16* __restrict__ bh, u16* __restrict__ bl, int n4each) {
    int i = blockIdx.x * 256 + threadIdx.x;
    const float* in = (i < n4each) ? a : b;
    u16* hi = (i < n4each) ? ah : bh;
    u16* lo = (i < n4each) ? al : bl;
    int j = (i < n4each) ? i : i - n4each;
    if (j >= n4each) return;
    const float4 v = reinterpret_cast<const float4*>(in)[j];
    u16 h0 = f2bf(v.x), h1 = f2bf(v.y), h2 = f2bf(v.z), h3 = f2bf(v.w);
    reinterpret_cast<ushort4*>(hi)[j] = make_ushort4(h0, h1, h2, h3);
    reinterpret_cast<ushort4*>(lo)[j] =
        make_ushort4(f2bf(v.x - bf2f(h0)), f2bf(v.y - bf2f(h1)),
                     f2bf(v.z - bf2f(h2)), f2bf(v.w - bf2f(h3)));
}

// ------------- transpose + split: in (R x C) f32 -> out (C x R) bf16 -------
template <bool WITH_LO>
__global__ __launch_bounds__(256) void k_tsplit(const float* __restrict__ in,
                                                u16* __restrict__ oh,
                                                u16* __restrict__ ol,
                                                int R, int C) {
    __shared__ float tile[32][33];
    int tx = threadIdx.x, ty = threadIdx.y;  // 32 x 8
    int c0 = blockIdx.x * 32, r0 = blockIdx.y * 32;
#pragma unroll
    for (int r = 0; r < 4; r++)
        tile[ty + r * 8][tx] = in[(size_t)(r0 + ty + r * 8) * C + (c0 + tx)];
    __syncthreads();
#pragma unroll
    for (int r = 0; r < 4; r++) {
        float v = tile[tx][ty + r * 8];
        size_t o = (size_t)(c0 + ty + r * 8) * R + (r0 + tx);
        u16 h = f2bf(v);
        oh[o] = h;
        if constexpr (WITH_LO) ol[o] = f2bf(v - bf2f(h));
    }
}

// ---- reduce 4 fp32 partials + split -> hi/lo bf16 (for Mt) ----------------
__global__ __launch_bounds__(256) void k_rsplit(
    const float* __restrict__ m0, const float* __restrict__ m1,
    const float* __restrict__ m2, const float* __restrict__ m3,
    u16* __restrict__ hi, u16* __restrict__ lo, int n4) {
    int i = blockIdx.x * 256 + threadIdx.x;
    if (i >= n4) return;
    float4 a = reinterpret_cast<const float4*>(m0)[i];
    float4 b = reinterpret_cast<const float4*>(m1)[i];
    float4 c = reinterpret_cast<const float4*>(m2)[i];
    float4 d = reinterpret_cast<const float4*>(m3)[i];
    float4 v = make_float4(a.x + b.x + c.x + d.x, a.y + b.y + c.y + d.y,
                           a.z + b.z + c.z + d.z, a.w + b.w + c.w + d.w);
    u16 h0 = f2bf(v.x), h1 = f2bf(v.y), h2 = f2bf(v.z), h3 = f2bf(v.w);
    reinterpret_cast<ushort4*>(hi)[i] = make_ushort4(h0, h1, h2, h3);
    reinterpret_cast<ushort4*>(lo)[i] =
        make_ushort4(f2bf(v.x - bf2f(h0)), f2bf(v.y - bf2f(h1)),
                     f2bf(v.z - bf2f(h2)), f2bf(v.w - bf2f(h3)));
}

// ---------------- GEMM core: 128x128 tile, BK=32, 32x32x16 MFMA ------------
// A[M,K] row-major (hi[,lo]), B as Bt[N,K] row-major (hi[,lo]).
// Wave covers 64x64 via 2x2 tiles of 32x32. LDS per tile: [128 rows][32 k].
template <int TERMS>
__device__ __forceinline__ void gemm_core(
    u16* smem,
    const u16* __restrict__ Ah, const u16* __restrict__ Al,
    const u16* __restrict__ Bh, const u16* __restrict__ Bl,
    int K, int kbeg, int kend, int rowA0, int rowB0,
    int tid, f32x16 (&acc)[2][2]) {
    constexpr int NB = (TERMS == 3) ? 2 : 1;
    const int lane = tid & 63, wv = tid >> 6;
    const int wm = (wv >> 1) * 64, wn = (wv & 1) * 64;
    const int l31 = lane & 31, lh = lane >> 5;

    const u16* srcs[2 * NB];
    if constexpr (TERMS == 3) {
        srcs[0] = Ah + (size_t)rowA0 * K;
        srcs[1] = Al + (size_t)rowA0 * K;
        srcs[2] = Bh + (size_t)rowB0 * K;
        srcs[3] = Bl + (size_t)rowB0 * K;
    } else {
        srcs[0] = Ah + (size_t)rowA0 * K;
        srcs[1] = Bh + (size_t)rowB0 * K;
    }
    const u16* sAh = smem;
    const u16* sAl = smem + 4096;
    const u16* sBh = smem + ((TERMS == 3) ? 8192 : 4096);
    const u16* sBl = smem + 12288;

    for (int k0 = kbeg; k0 < kend; k0 += 32) {
#pragma unroll
        for (int i = 0; i < 4 * NB; i++) {
            int c = ((i & 1) << 8) + (wv << 6) + lane;  // chunk within tile
            int m = c >> 2, kb = c & 3;
            const u16* g = srcs[i >> 1] + (size_t)m * K + (k0 + kb * 8);
            u16* l = smem + (size_t)((i << 8) + (wv << 6) + lane) * 8;
            gll16(g, l);
        }
        __syncthreads();

#pragma unroll
        for (int ks = 0; ks < 2; ks++) {
            bf16x8 a[2], b[2];
#pragma unroll
            for (int i = 0; i < 2; i++) {
                a[i] = *(const bf16x8*)(sAh + (wm + i * 32 + l31) * 32 + ks * 16 + lh * 8);
                b[i] = *(const bf16x8*)(sBh + (wn + i * 32 + l31) * 32 + ks * 16 + lh * 8);
            }
            if constexpr (TERMS == 3) {
                bf16x8 al2[2], bl2[2];
#pragma unroll
                for (int i = 0; i < 2; i++) {
                    al2[i] = *(const bf16x8*)(sAl + (wm + i * 32 + l31) * 32 + ks * 16 + lh * 8);
                    bl2[i] = *(const bf16x8*)(sBl + (wn + i * 32 + l31) * 32 + ks * 16 + lh * 8);
                }
#pragma unroll
                for (int mi = 0; mi < 2; mi++)
#pragma unroll
                    for (int ni = 0; ni < 2; ni++) {
                        acc[mi][ni] = __builtin_amdgcn_mfma_f32_32x32x16_bf16(a[mi], b[ni], acc[mi][ni], 0, 0, 0);
                        acc[mi][ni] = __builtin_amdgcn_mfma_f32_32x32x16_bf16(a[mi], bl2[ni], acc[mi][ni], 0, 0, 0);
                        acc[mi][ni] = __builtin_amdgcn_mfma_f32_32x32x16_bf16(al2[mi], b[ni], acc[mi][ni], 0, 0, 0);
                    }
            } else {
#pragma unroll
                for (int mi = 0; mi < 2; mi++)
#pragma unroll
                    for (int ni = 0; ni < 2; ni++)
                        acc[mi][ni] = __builtin_amdgcn_mfma_f32_32x32x16_bf16(a[mi], b[ni], acc[mi][ni], 0, 0, 0);
            }
        }
        __syncthreads();
    }
}

// C/D 32x32 layout: col = lane&31, row = (r&3) + 8*(r>>2) + 4*(lane>>5)
#define EPILOGUE_32(BODY)                                                    \
    const int lane = threadIdx.x & 63, wv = threadIdx.x >> 6;                \
    const int wm = (wv >> 1) * 64, wn = (wv & 1) * 64;                       \
    const int l31 = lane & 31, lh4 = (lane >> 5) * 4;                        \
    _Pragma("unroll")                                                        \
    for (int mi = 0; mi < 2; mi++)                                           \
        _Pragma("unroll")                                                    \
        for (int ni = 0; ni < 2; ni++)                                       \
            _Pragma("unroll")                                                \
            for (int r = 0; r < 16; r++) {                                   \
                int row = wm + mi * 32 + (r & 3) + 8 * (r >> 2) + lh4;       \
                int col = wn + ni * 32 + l31;                                \
                float val = acc[mi][ni][r];                                  \
                BODY                                                         \
            }

// ---- Mt partials: Mp[z] = Wk*Wq^T over K-slice z (split-K=4, plain store) --
__global__ __launch_bounds__(256) void k_gemm_m(
    const u16* __restrict__ Wkh, const u16* __restrict__ Wkl,
    const u16* __restrict__ Wqh, const u16* __restrict__ Wql,
    float* __restrict__ Mp) {
    __shared__ u16 smem[16384];
    f32x16 acc[2][2] = {};
    const int rowA0 = blockIdx.y * 128, rowB0 = blockIdx.x * 128;
    const int kbeg = blockIdx.z * 256;
    float* Mz = Mp + (size_t)blockIdx.z * EDIM * EDIM;
    gemm_core<3>(smem, Wkh, Wkl, Wqh, Wql, EDIM, kbeg, kbeg + 256, rowA0, rowB0, threadIdx.x, acc);
    EPILOGUE_32({
        Mz[(size_t)(rowA0 + row) * EDIM + (rowB0 + col)] = val;
    })
}

// ---- merged: b<256: y = x*M^T (TERMS=3, split epi); else Vt = Wv^T*x^T ----
__global__ __launch_bounds__(256) void k_gemm_yv(
    const u16* __restrict__ xh, const u16* __restrict__ xl,
    const u16* __restrict__ Mth, const u16* __restrict__ Mtl,
    const u16* __restrict__ Wvth,
    u16* __restrict__ yh, u16* __restrict__ yl, u16* __restrict__ Vt) {
    __shared__ u16 smem[16384];
    f32x16 acc[2][2] = {};
    const int b = blockIdx.x;
    if (b < 256) {
        int tm = b >> 3, tn = b & 7;
        gemm_core<3>(smem, xh, xl, Mth, Mtl, EDIM, 0, EDIM, tm * 128, tn * 128, threadIdx.x, acc);
        EPILOGUE_32({
            size_t o = (size_t)(tm * 128 + row) * EDIM + (tn * 128 + col);
            u16 h = f2bf(val);
            yh[o] = h;
            yl[o] = f2bf(val - bf2f(h));
        })
    } else {
        int b2 = b - 256;
        int tm = b2 & 7, tn = b2 >> 3;  // Vt is [1024=d rows][4096=s cols]
        gemm_core<1>(smem, Wvth, nullptr, xh, nullptr, EDIM, 0, EDIM, tm * 128, tn * 128, threadIdx.x, acc);
        EPILOGUE_32({
            Vt[(size_t)(tm * 128 + row) * SLEN + (tn * 128 + col)] = f2bf(val);
        })
    }
}

// ---- S = y*x^T /32, lower-tri tiles, split-K=2, packed partial outputs ----
__global__ __launch_bounds__(256) void k_gemm_s(
    const u16* __restrict__ yh, const u16* __restrict__ yl,
    const u16* __restrict__ xh, const u16* __restrict__ xl,
    float* __restrict__ Spk0, float* __restrict__ Spk1) {
    __shared__ u16 smem[16384];
    int b = blockIdx.x;
    int half = (b >= 528) ? 1 : 0;
    int t = b - half * 528;
    int ti = (int)((sqrtf(8.0f * (float)t + 1.0f) - 1.0f) * 0.5f);
    while ((ti + 1) * (ti + 2) / 2 <= t) ti++;
    while (ti * (ti + 1) / 2 > t) ti--;
    int tm = ti, tn = t - ti * (ti + 1) / 2;
    f32x16 acc[2][2] = {};
    gemm_core<3>(smem, yh, yl, xh, xl, EDIM, half * 512, half * 512 + 512,
                 tm * 128, tn * 128, threadIdx.x, acc);
    float* Cb = (half ? Spk1 : Spk0) + (size_t)t * 16384;
    EPILOGUE_32({
        Cb[row * 128 + col] = val * 0.03125f;
    })
}

// ---------------- PV GEMM: split-K (KC=1024), atomic for tm>=8 -------------
__global__ __launch_bounds__(256) void k_gemm_pv(
    const u16* __restrict__ P, const u16* __restrict__ Vt,
    float* __restrict__ C) {
    __shared__ u16 smem[8192];
    int tn = blockIdx.x;
    int y = blockIdx.y, tm = 0;
    for (;;) {
        int nc = (tm + 8) >> 3;  // ceil((tm+1)/8)
        if (y < nc) break;
        y -= nc; tm++;
    }
    int kbeg = y * 1024;
    int kend = min((tm + 1) * 128, kbeg + 1024);
    f32x16 acc[2][2] = {};
    gemm_core<1>(smem, P, nullptr, Vt, nullptr, SLEN, kbeg, kend, tm * 128, tn * 128, threadIdx.x, acc);
    bool multi = (tm >= 8);
    EPILOGUE_32({
        size_t o = (size_t)(tm * 128 + row) * EDIM + (tn * 128 + col);
        if (multi) atomicAdd(&C[o], val);
        else       C[o] = val;
    })
}

// ---------------- row softmax over packed S halves -> P bf16 ----------------
__global__ __launch_bounds__(256) void k_softmax(const float* __restrict__ Spk0,
                                                 const float* __restrict__ Spk1,
                                                 u16* __restrict__ P) {
    __shared__ float buf[SLEN];
    __shared__ float red[4];
    int row = blockIdx.x;
    int tid = threadIdx.x;
    int lane = tid & 63, wid = tid >> 6;
    int n = row + 1;
    int tm = row >> 7, rl = row & 127;
    size_t base = (size_t)(tm * (tm + 1) / 2) * 16384 + rl * 128;
    const float* srow0 = Spk0 + base;
    const float* srow1 = Spk1 + base;

    float m = -3.0e38f;
    for (int j = tid; j < n; j += 256) {
        size_t idx = (size_t)(j >> 7) * 16384 + (j & 127);
        float v = srow0[idx] + srow1[idx];
        buf[j] = v;
        m = fmaxf(m, v);
    }
#pragma unroll
    for (int o = 32; o; o >>= 1) m = fmaxf(m, __shfl_xor(m, o));
    if (lane == 0) red[wid] = m;
    __syncthreads();
    m = fmaxf(fmaxf(red[0], red[1]), fmaxf(red[2], red[3]));
    __syncthreads();

    float s = 0.f;
    for (int j = tid; j < n; j += 256) {
        float e = __expf(buf[j] - m);
        buf[j] = e;
        s += e;
    }
#pragma unroll
    for (int o = 32; o; o >>= 1) s += __shfl_xor(s, o);
    if (lane == 0) red[wid] = s;
    __syncthreads();
    s = red[0] + red[1] + red[2] + red[3];
    float inv = 1.0f / s;

    u16* prow = P + (size_t)row * SLEN;
    for (int j = tid; j < n; j += 256) prow[j] = f2bf(buf[j] * inv);
    // zero tail up to 128-boundary (PV stages it; P overlays dead xh..yl)
    int jend = ((row >> 7) + 1) << 7;
    for (int j = n + tid; j < jend; j += 256) prow[j] = 0;
}

// ---------------------------------------------------------------------------
extern "C" void kernel_launch(void* const* d_in, const int* in_sizes, int n_in,
                              void* d_out, int out_size, void* d_ws, size_t ws_size,
                              hipStream_t stream) {
    const float* x  = (const float*)d_in[0];
    const float* Wq = (const float*)d_in[1];
    const float* Wk = (const float*)d_in[2];
    const float* Wv = (const float*)d_in[3];
    float* out = (float*)d_out;
    char* ws = (char*)d_ws;
    const size_t MB = 1024 * 1024;

    // persistent regions
    u16* xh = (u16*)(ws + 0 * MB);     // 8MB, live until S-GEMM
    u16* xl = (u16*)(ws + 8 * MB);     // 8MB
    u16* yh = (u16*)(ws + 16 * MB);    // 8MB
    u16* yl = (u16*)(ws + 24 * MB);    // 8MB
    u16* Vt = (u16*)(ws + 32 * MB);    // 8MB, live until PV
    float* Spk0 = (float*)(ws + 40 * MB);  // 33MB  [40,73)
    float* Spk1 = (float*)(ws + 73 * MB);  // 33MB  [73,106)
    // transients inside [40,106) -- all dead before k_gemm_s writes Spk
    u16* Wqh  = (u16*)(ws + 40 * MB);
    u16* Wql  = (u16*)(ws + 42 * MB);
    u16* Wkh  = (u16*)(ws + 44 * MB);
    u16* Wkl  = (u16*)(ws + 46 * MB);
    u16* Wvth = (u16*)(ws + 48 * MB);
    float* Mp = (float*)(ws + 50 * MB);    // 4 x 4MB partials [50,66)
    u16* Mth  = (u16*)(ws + 66 * MB);
    u16* Mtl  = (u16*)(ws + 68 * MB);      // -70
    // P overlays xh..yl (dead after S-GEMM)
    u16* Pb = (u16*)(ws + 0 * MB);         // 32MB

    dim3 b256(256);
    dim3 tb(32, 8);

    // 1) splits / transpose
    k_split<<<4096, b256, 0, stream>>>(x, xh, xl, (SLEN * EDIM) / 4);
    k_split2<<<2048, b256, 0, stream>>>(Wq, Wk, Wqh, Wql, Wkh, Wkl, (EDIM * EDIM) / 4);
    k_tsplit<false><<<dim3(32, 32), tb, 0, stream>>>(Wv, Wvth, nullptr, EDIM, EDIM);

    // 2) Mt = Wk*Wq^T: 4 K-slice partials (plain stores) + fused reduce/split
    k_gemm_m<<<dim3(8, 8, 4), b256, 0, stream>>>(Wkh, Wkl, Wqh, Wql, Mp);
    k_rsplit<<<1024, b256, 0, stream>>>(Mp, Mp + EDIM * EDIM, Mp + 2 * EDIM * EDIM,
                                        Mp + 3 * EDIM * EDIM, Mth, Mtl, (EDIM * EDIM) / 4);

    // 3) y = x*M^T (split epi) + Vt = Wv^T*x^T, one 512-block dispatch
    k_gemm_yv<<<512, b256, 0, stream>>>(xh, xl, Mth, Mtl, Wvth, yh, yl, Vt);

    // 4) S = y*x^T /32, tri tiles, split-K=2 (1056 blocks)
    k_gemm_s<<<1056, b256, 0, stream>>>(yh, yl, xh, xl, Spk0, Spk1);

    // 5) softmax (sums the two K-halves) -> P bf16
    k_softmax<<<SLEN, b256, 0, stream>>>(Spk0, Spk1, Pb);

    // 6) out = P@V, split-K KC=1024 (grid 8 x 80), atomics for tm>=8
    hipMemsetAsync(d_out, 0, (size_t)out_size * sizeof(float), stream);
    k_gemm_pv<<<dim3(8, 80), b256, 0, stream>>>(Pb, Vt, out);
}